// Round 1
// baseline (3058.601 us; speedup 1.0000x reference)
//
#include <hip/hip_runtime.h>
#include <math.h>

#define HH 96
#define WW 128
#define DD 64
#define BB 8
#define KK 7
#define CC 32
#define HWSZ (HH*WW)
#define EPSF 1e-8f
#define TILES (HWSZ/256)   // 48 tiles of 256 pixels

__global__ __launch_bounds__(256) void cost_volume_kernel(
    const float* __restrict__ cur,      // (B,C,H,W)
    const float* __restrict__ src,      // (B,K,C,H,W)
    const float* __restrict__ Emat,     // (B,K,4,4)
    const float* __restrict__ Kmat,     // (B,K,4,4)
    const float* __restrict__ invK,     // (B,4,4)
    const float* __restrict__ mnp,      // (B)
    const float* __restrict__ mxp,      // (B)
    float* __restrict__ out)            // (B,D,H,W)
{
    // block decode: blk = ((b*D + d)*TILES + tile)
    int blk  = blockIdx.x;
    int tile = blk % TILES;
    int bd   = blk / TILES;
    int d    = bd % DD;
    int b    = bd / DD;

    __shared__ float sM[KK][12];   // per-k fused 3x4: cam = depth*(M[0:3]*pix) + M[col 3]
    __shared__ float sDepth;

    if (threadIdx.x < KK) {
        int k = threadIdx.x;
        const float* Km = Kmat + (size_t)(b*KK + k)*16;
        const float* Em = Emat + (size_t)(b*KK + k)*16;
        float P[3][4];
        #pragma unroll
        for (int i = 0; i < 3; ++i)
            #pragma unroll
            for (int j = 0; j < 4; ++j) {
                float s = 0.f;
                #pragma unroll
                for (int l = 0; l < 4; ++l) s = fmaf(Km[i*4+l], Em[l*4+j], s);
                P[i][j] = s;
            }
        const float* iK = invK + (size_t)b*16;
        #pragma unroll
        for (int i = 0; i < 3; ++i) {
            #pragma unroll
            for (int j = 0; j < 3; ++j) {
                float s = 0.f;
                #pragma unroll
                for (int l = 0; l < 3; ++l) s = fmaf(P[i][l], iK[l*4+j], s);
                sM[k][i*4+j] = s;
            }
            sM[k][i*4+3] = P[i][3];
        }
    }
    if (threadIdx.x == KK) {
        float mnb = mnp[b], mxb = mxp[b];
        float ramp = (float)d / (float)(DD - 1);
        sDepth = expf(logf(mnb) + logf(mxb / mnb) * ramp);
    }
    __syncthreads();

    int p  = tile*256 + threadIdx.x;
    int px = p & (WW - 1);
    int py = p >> 7;           // W = 128
    float fx = (float)px + 0.5f;
    float fy = (float)py + 0.5f;
    float depth = sDepth;

    // current-frame feature vector in registers
    float curv[CC];
    const float* curp = cur + (size_t)b*CC*HWSZ + p;
    #pragma unroll
    for (int c = 0; c < CC; ++c) curv[c] = curp[(size_t)c*HWSZ];

    float acc = 0.f;

    for (int k = 0; k < KK; ++k) {
        const float* m = sM[k];
        float q0 = fmaf(m[0], fx, fmaf(m[1], fy, m[2]));
        float q1 = fmaf(m[4], fx, fmaf(m[5], fy, m[6]));
        float q2 = fmaf(m[8], fx, fmaf(m[9], fy, m[10]));
        float cam0 = fmaf(depth, q0, m[3]);
        float cam1 = fmaf(depth, q1, m[7]);
        float zraw = fmaf(depth, q2, m[11]);
        float z     = zraw + EPSF;
        float scale = (fabsf(zraw) > EPSF) ? (1.f / z) : 1.f;
        float u = cam0 * scale;
        float v = cam1 * scale;
        // grid-sample algebra: x = (gx+1)*0.5*W - 0.5 with gx = 2u/W - 1  ->  x = u - 0.5
        float x = u - 0.5f;
        float y = v - 0.5f;
        float x0f = floorf(x), y0f = floorf(y);
        float wx1 = x - x0f,  wy1 = y - y0f;
        float wx0 = 1.f - wx1, wy0 = 1.f - wy1;
        bool vx0 = (x0f >= 0.f)       && (x0f <= (float)(WW-1));
        bool vx1 = (x0f + 1.f >= 0.f) && (x0f + 1.f <= (float)(WW-1));
        bool vy0 = (y0f >= 0.f)       && (y0f <= (float)(HH-1));
        bool vy1 = (y0f + 1.f >= 0.f) && (y0f + 1.f <= (float)(HH-1));
        float w00 = (vx0 && vy0) ? wx0*wy0 : 0.f;
        float w01 = (vx1 && vy0) ? wx1*wy0 : 0.f;
        float w10 = (vx0 && vy1) ? wx0*wy1 : 0.f;
        float w11 = (vx1 && vy1) ? wx1*wy1 : 0.f;
        int ix0 = (int)fminf(fmaxf(x0f,      0.f), (float)(WW-1));
        int ix1 = (int)fminf(fmaxf(x0f + 1.f,0.f), (float)(WW-1));
        int iy0 = (int)fminf(fmaxf(y0f,      0.f), (float)(HH-1));
        int iy1 = (int)fminf(fmaxf(y0f + 1.f,0.f), (float)(HH-1));

        const float* sb = src + (size_t)(b*KK + k)*CC*HWSZ;
        int o00 = iy0*WW + ix0;
        int o01 = iy0*WW + ix1;
        int o10 = iy1*WW + ix0;
        int o11 = iy1*WW + ix1;

        float a00 = 0.f, a01 = 0.f, a10 = 0.f, a11 = 0.f;
        #pragma unroll 8
        for (int c = 0; c < CC; ++c) {
            const float* sc = sb + (size_t)c*HWSZ;
            a00 = fmaf(curv[c], sc[o00], a00);
            a01 = fmaf(curv[c], sc[o01], a01);
            a10 = fmaf(curv[c], sc[o10], a10);
            a11 = fmaf(curv[c], sc[o11], a11);
        }
        float dotk = w00*a00 + w01*a01 + w10*a10 + w11*a11;
        acc += (z > 0.f) ? dotk : 0.f;
    }

    out[(size_t)(b*DD + d)*HWSZ + p] = acc;
}

extern "C" void kernel_launch(void* const* d_in, const int* in_sizes, int n_in,
                              void* d_out, int out_size, void* d_ws, size_t ws_size,
                              hipStream_t stream) {
    const float* cur   = (const float*)d_in[0];
    const float* srcf  = (const float*)d_in[1];
    const float* Emat  = (const float*)d_in[2];
    const float* Kmat  = (const float*)d_in[3];
    const float* invK  = (const float*)d_in[4];
    const float* mn    = (const float*)d_in[5];
    const float* mx    = (const float*)d_in[6];
    float* out = (float*)d_out;

    dim3 grid(BB * DD * TILES);
    dim3 block(256);
    cost_volume_kernel<<<grid, block, 0, stream>>>(cur, srcf, Emat, Kmat, invK, mn, mx, out);
}

// Round 2
// 2203.009 us; speedup vs baseline: 1.3884x; 1.3884x over previous
//
#include <hip/hip_runtime.h>
#include <math.h>

#define HH 96
#define WW 128
#define DD 64
#define BB 8
#define KK 7
#define CC 32
#define HWSZ (HH*WW)
#define EPSF 1e-8f
#define TILES (HWSZ/256)     // 48 tiles of 256 pixels
#define ND 4                 // depth planes per thread
#define DGROUPS (DD/ND)      // 16

// ---------- transpose (B,K,C,H,W) -> (B,K,H*W,C) ----------
__global__ __launch_bounds__(256) void transpose_src(const float* __restrict__ in,
                                                     float* __restrict__ outT)
{
    __shared__ float t[CC][33];
    int blk    = blockIdx.x;
    int hwTile = blk % (HWSZ/32);
    int v      = blk / (HWSZ/32);      // b*K + k
    int hw0    = hwTile*32;
    const float* ip = in   + (size_t)v*CC*HWSZ;
    float*       op = outT + (size_t)v*HWSZ*CC;
    int j = threadIdx.x & 31;
    int r = threadIdx.x >> 5;          // 0..7
    #pragma unroll
    for (int i = 0; i < 4; ++i) {
        int c = r + i*8;
        t[c][j] = ip[(size_t)c*HWSZ + hw0 + j];   // coalesced read
    }
    __syncthreads();
    #pragma unroll
    for (int i = 0; i < 4; ++i) {
        int row = r + i*8;
        op[(size_t)(hw0+row)*CC + j] = t[j][row]; // 128B-contiguous writes
    }
}

// ---------- main cost-volume kernel ----------
template<bool NHWC>
__global__ __launch_bounds__(256) void cv_kernel(
    const float* __restrict__ cur,      // (B,C,H,W)
    const float* __restrict__ srcv,     // NHWC ? (B,K,HW,C) : (B,K,C,HW)
    const float* __restrict__ Emat,     // (B,K,4,4)
    const float* __restrict__ Kmat,     // (B,K,4,4)
    const float* __restrict__ invK,     // (B,4,4)
    const float* __restrict__ mnp,
    const float* __restrict__ mxp,
    float* __restrict__ out)            // (B,D,H,W)
{
    int blk  = blockIdx.x;
    int tile = blk % TILES;
    int t2   = blk / TILES;
    int g    = t2 % DGROUPS;
    int b    = t2 / DGROUPS;

    __shared__ float sM[KK][12];
    if (threadIdx.x < KK) {
        int k = threadIdx.x;
        const float* Km = Kmat + (size_t)(b*KK + k)*16;
        const float* Em = Emat + (size_t)(b*KK + k)*16;
        float P[3][4];
        #pragma unroll
        for (int i = 0; i < 3; ++i)
            #pragma unroll
            for (int j = 0; j < 4; ++j) {
                float s = 0.f;
                #pragma unroll
                for (int l = 0; l < 4; ++l) s = fmaf(Km[i*4+l], Em[l*4+j], s);
                P[i][j] = s;
            }
        const float* iK = invK + (size_t)b*16;
        #pragma unroll
        for (int i = 0; i < 3; ++i) {
            #pragma unroll
            for (int j = 0; j < 3; ++j) {
                float s = 0.f;
                #pragma unroll
                for (int l = 0; l < 3; ++l) s = fmaf(P[i][l], iK[l*4+j], s);
                sM[k][i*4+j] = s;
            }
            sM[k][i*4+3] = P[i][3];
        }
    }
    __syncthreads();

    int p  = tile*256 + threadIdx.x;
    float fx = (float)(p & (WW-1)) + 0.5f;
    float fy = (float)(p >> 7) + 0.5f;

    float curv[CC];
    const float* curp = cur + (size_t)b*CC*HWSZ + p;
    #pragma unroll
    for (int c = 0; c < CC; ++c) curv[c] = curp[(size_t)c*HWSZ];

    float mnb = mnp[b];
    float lmn = logf(mnb);
    float lr  = logf(mxp[b] / mnb);
    float depths[ND];
    #pragma unroll
    for (int dd = 0; dd < ND; ++dd)
        depths[dd] = expf(fmaf(lr, (float)(g*ND + dd) * (1.f/63.f), lmn));

    float acc[ND];
    #pragma unroll
    for (int dd = 0; dd < ND; ++dd) acc[dd] = 0.f;

    for (int k = 0; k < KK; ++k) {
        float m0 = sM[k][0], m1 = sM[k][1], m2  = sM[k][2],  m3  = sM[k][3];
        float m4 = sM[k][4], m5 = sM[k][5], m6  = sM[k][6],  m7  = sM[k][7];
        float m8 = sM[k][8], m9 = sM[k][9], m10 = sM[k][10], m11 = sM[k][11];
        float q0 = fmaf(m0, fx, fmaf(m1, fy, m2));
        float q1 = fmaf(m4, fx, fmaf(m5, fy, m6));
        float q2 = fmaf(m8, fx, fmaf(m9, fy, m10));
        const float* sb = srcv + (size_t)(b*KK + k)*CC*HWSZ;

        #pragma unroll
        for (int dd = 0; dd < ND; ++dd) {
            float depth = depths[dd];
            float cam0 = fmaf(depth, q0, m3);
            float cam1 = fmaf(depth, q1, m7);
            float zraw = fmaf(depth, q2, m11);
            float z     = zraw + EPSF;
            float scale = (fabsf(zraw) > EPSF) ? (1.f / z) : 1.f;
            float x = cam0 * scale - 0.5f;   // grid-sample algebra collapses
            float y = cam1 * scale - 0.5f;
            float x0f = floorf(x), y0f = floorf(y);
            float wx1 = x - x0f,  wy1 = y - y0f;
            float wx0 = 1.f - wx1, wy0 = 1.f - wy1;
            bool vx0 = (x0f >= 0.f)       && (x0f <= (float)(WW-1));
            bool vx1 = (x0f + 1.f >= 0.f) && (x0f + 1.f <= (float)(WW-1));
            bool vy0 = (y0f >= 0.f)       && (y0f <= (float)(HH-1));
            bool vy1 = (y0f + 1.f >= 0.f) && (y0f + 1.f <= (float)(HH-1));
            float w00 = (vx0 && vy0) ? wx0*wy0 : 0.f;
            float w01 = (vx1 && vy0) ? wx1*wy0 : 0.f;
            float w10 = (vx0 && vy1) ? wx0*wy1 : 0.f;
            float w11 = (vx1 && vy1) ? wx1*wy1 : 0.f;
            int ix0 = (int)fminf(fmaxf(x0f,       0.f), (float)(WW-1));
            int ix1 = (int)fminf(fmaxf(x0f + 1.f, 0.f), (float)(WW-1));
            int iy0 = (int)fminf(fmaxf(y0f,       0.f), (float)(HH-1));
            int iy1 = (int)fminf(fmaxf(y0f + 1.f, 0.f), (float)(HH-1));
            int o00 = iy0*WW + ix0;
            int o01 = iy0*WW + ix1;
            int o10 = iy1*WW + ix0;
            int o11 = iy1*WW + ix1;

            float dotk;
            if constexpr (NHWC) {
                const float* s00 = sb + (size_t)o00*CC;
                const float* s01 = sb + (size_t)o01*CC;
                const float* s10 = sb + (size_t)o10*CC;
                const float* s11 = sb + (size_t)o11*CC;
                float a00[4] = {0,0,0,0}, a01[4] = {0,0,0,0};
                float a10[4] = {0,0,0,0}, a11[4] = {0,0,0,0};
                #pragma unroll
                for (int cc = 0; cc < 8; ++cc) {
                    float4 t00 = *reinterpret_cast<const float4*>(s00 + cc*4);
                    float4 t01 = *reinterpret_cast<const float4*>(s01 + cc*4);
                    float4 t10 = *reinterpret_cast<const float4*>(s10 + cc*4);
                    float4 t11 = *reinterpret_cast<const float4*>(s11 + cc*4);
                    float c0 = curv[4*cc+0], c1 = curv[4*cc+1];
                    float c2 = curv[4*cc+2], c3 = curv[4*cc+3];
                    a00[0] = fmaf(c0, t00.x, a00[0]); a00[1] = fmaf(c1, t00.y, a00[1]);
                    a00[2] = fmaf(c2, t00.z, a00[2]); a00[3] = fmaf(c3, t00.w, a00[3]);
                    a01[0] = fmaf(c0, t01.x, a01[0]); a01[1] = fmaf(c1, t01.y, a01[1]);
                    a01[2] = fmaf(c2, t01.z, a01[2]); a01[3] = fmaf(c3, t01.w, a01[3]);
                    a10[0] = fmaf(c0, t10.x, a10[0]); a10[1] = fmaf(c1, t10.y, a10[1]);
                    a10[2] = fmaf(c2, t10.z, a10[2]); a10[3] = fmaf(c3, t10.w, a10[3]);
                    a11[0] = fmaf(c0, t11.x, a11[0]); a11[1] = fmaf(c1, t11.y, a11[1]);
                    a11[2] = fmaf(c2, t11.z, a11[2]); a11[3] = fmaf(c3, t11.w, a11[3]);
                }
                dotk = w00*(a00[0]+a00[1]+a00[2]+a00[3])
                     + w01*(a01[0]+a01[1]+a01[2]+a01[3])
                     + w10*(a10[0]+a10[1]+a10[2]+a10[3])
                     + w11*(a11[0]+a11[1]+a11[2]+a11[3]);
            } else {
                float a00 = 0.f, a01 = 0.f, a10 = 0.f, a11 = 0.f;
                #pragma unroll 8
                for (int c = 0; c < CC; ++c) {
                    const float* sc = sb + (size_t)c*HWSZ;
                    a00 = fmaf(curv[c], sc[o00], a00);
                    a01 = fmaf(curv[c], sc[o01], a01);
                    a10 = fmaf(curv[c], sc[o10], a10);
                    a11 = fmaf(curv[c], sc[o11], a11);
                }
                dotk = w00*a00 + w01*a01 + w10*a10 + w11*a11;
            }
            acc[dd] += (z > 0.f) ? dotk : 0.f;
        }
    }

    #pragma unroll
    for (int dd = 0; dd < ND; ++dd)
        out[(size_t)(b*DD + g*ND + dd)*HWSZ + p] = acc[dd];
}

extern "C" void kernel_launch(void* const* d_in, const int* in_sizes, int n_in,
                              void* d_out, int out_size, void* d_ws, size_t ws_size,
                              hipStream_t stream) {
    const float* cur   = (const float*)d_in[0];
    const float* srcf  = (const float*)d_in[1];
    const float* Emat  = (const float*)d_in[2];
    const float* Kmat  = (const float*)d_in[3];
    const float* invK  = (const float*)d_in[4];
    const float* mn    = (const float*)d_in[5];
    const float* mx    = (const float*)d_in[6];
    float* out = (float*)d_out;

    const size_t needT = (size_t)BB*KK*HWSZ*CC*sizeof(float);  // 88 MB
    dim3 block(256);
    dim3 grid(BB * DGROUPS * TILES);   // 8*16*48 = 6144

    if (ws_size >= needT) {
        float* srcT = (float*)d_ws;
        transpose_src<<<dim3(BB*KK*(HWSZ/32)), block, 0, stream>>>(srcf, srcT);
        cv_kernel<true><<<grid, block, 0, stream>>>(cur, srcT, Emat, Kmat, invK, mn, mx, out);
    } else {
        cv_kernel<false><<<grid, block, 0, stream>>>(cur, srcf, Emat, Kmat, invK, mn, mx, out);
    }
}

// Round 3
// 2094.146 us; speedup vs baseline: 1.4605x; 1.0520x over previous
//
#include <hip/hip_runtime.h>
#include <math.h>

#define HH 96
#define WW 128
#define DD 64
#define BB 8
#define KK 7
#define CC 32
#define HWSZ (HH*WW)
#define EPSF 1e-8f
#define TILES (HWSZ/256)     // 48
#define ND 2
#define DG (DD/ND)           // 32

static __device__ __forceinline__ float bf_lo(unsigned u){ return __uint_as_float(u << 16); }
static __device__ __forceinline__ float bf_hi(unsigned u){ return __uint_as_float(u & 0xffff0000u); }
static __device__ __forceinline__ unsigned f2bf(float f){
    unsigned u = __float_as_uint(f);
    return (u + 0x7fffu + ((u >> 16) & 1u)) >> 16;   // RNE
}

// ---------- pack src: (B*K, C, HW) fp32 -> (B*K, HW, C) bf16 ----------
__global__ __launch_bounds__(256) void pack_src(const float* __restrict__ in,
                                                unsigned short* __restrict__ outT)
{
    __shared__ float t[CC][33];
    int blk    = blockIdx.x;
    int hwTile = blk % (HWSZ/32);
    int v      = blk / (HWSZ/32);
    int hw0    = hwTile*32;
    const float* ip = in + (size_t)v*CC*HWSZ;
    unsigned short* op = outT + (size_t)v*HWSZ*CC;
    int j = threadIdx.x & 31;
    int r = threadIdx.x >> 5;
    #pragma unroll
    for (int i = 0; i < 4; ++i) {
        int c = r + i*8;
        t[c][j] = ip[(size_t)c*HWSZ + hw0 + j];
    }
    __syncthreads();
    int row = threadIdx.x >> 3;       // 0..31 pixel within tile
    int cg  = threadIdx.x & 7;        // 0..7 channel group of 4
    int c0  = cg*4;
    float f0 = t[c0+0][row], f1 = t[c0+1][row];
    float f2 = t[c0+2][row], f3 = t[c0+3][row];
    unsigned u0 = (f2bf(f1) << 16) | f2bf(f0);
    unsigned u1 = (f2bf(f3) << 16) | f2bf(f2);
    *reinterpret_cast<uint2*>(op + (size_t)(hw0+row)*CC + c0) = make_uint2(u0, u1);
}

// ---------- pack cur: (B, C, HW) fp32 -> (B, HW, C) fp32 ----------
__global__ __launch_bounds__(256) void pack_cur(const float* __restrict__ in,
                                                float* __restrict__ outT)
{
    __shared__ float t[CC][33];
    int blk    = blockIdx.x;
    int hwTile = blk % (HWSZ/32);
    int v      = blk / (HWSZ/32);
    int hw0    = hwTile*32;
    const float* ip = in + (size_t)v*CC*HWSZ;
    float*       op = outT + (size_t)v*HWSZ*CC;
    int j = threadIdx.x & 31;
    int r = threadIdx.x >> 5;
    #pragma unroll
    for (int i = 0; i < 4; ++i) {
        int c = r + i*8;
        t[c][j] = ip[(size_t)c*HWSZ + hw0 + j];
    }
    __syncthreads();
    int row = threadIdx.x >> 3;
    int cg  = threadIdx.x & 7;
    int c0  = cg*4;
    float4 f = make_float4(t[c0+0][row], t[c0+1][row], t[c0+2][row], t[c0+3][row]);
    *reinterpret_cast<float4*>(op + (size_t)(hw0+row)*CC + c0) = f;
}

// ---------- per-depth projection result ----------
struct Tap {
    unsigned o0, o1, o2, o3;   // byte offsets into src slice
    float w0, w1, w2, w3;      // bilinear weights * validity * (z>0)
};

static __device__ __forceinline__ Tap project(float depth, float q0, float q1, float q2,
                                              float m3, float m7, float m11)
{
    float cam0 = fmaf(depth, q0, m3);
    float cam1 = fmaf(depth, q1, m7);
    float zraw = fmaf(depth, q2, m11);
    float z     = zraw + EPSF;
    float scale = (fabsf(zraw) > EPSF) ? (1.f / z) : 1.f;
    float x = cam0 * scale - 0.5f;
    float y = cam1 * scale - 0.5f;
    float x0f = floorf(x), y0f = floorf(y);
    float wx1 = x - x0f,  wy1 = y - y0f;
    float wx0 = 1.f - wx1, wy0 = 1.f - wy1;
    bool vx0 = (x0f >= 0.f)       && (x0f <= (float)(WW-1));
    bool vx1 = (x0f + 1.f >= 0.f) && (x0f + 1.f <= (float)(WW-1));
    bool vy0 = (y0f >= 0.f)       && (y0f <= (float)(HH-1));
    bool vy1 = (y0f + 1.f >= 0.f) && (y0f + 1.f <= (float)(HH-1));
    float zm = (z > 0.f) ? 1.f : 0.f;
    Tap t;
    t.w0 = (vx0 && vy0) ? wx0*wy0*zm : 0.f;
    t.w1 = (vx1 && vy0) ? wx1*wy0*zm : 0.f;
    t.w2 = (vx0 && vy1) ? wx0*wy1*zm : 0.f;
    t.w3 = (vx1 && vy1) ? wx1*wy1*zm : 0.f;
    int ix0 = (int)fminf(fmaxf(x0f,       0.f), (float)(WW-1));
    int ix1 = (int)fminf(fmaxf(x0f + 1.f, 0.f), (float)(WW-1));
    int iy0 = (int)fminf(fmaxf(y0f,       0.f), (float)(HH-1));
    int iy1 = (int)fminf(fmaxf(y0f + 1.f, 0.f), (float)(HH-1));
    t.o0 = (unsigned)(iy0*WW + ix0) * (CC*2);   // bf16: 64B per pixel
    t.o1 = (unsigned)(iy0*WW + ix1) * (CC*2);
    t.o2 = (unsigned)(iy1*WW + ix0) * (CC*2);
    t.o3 = (unsigned)(iy1*WW + ix1) * (CC*2);
    return t;
}

#define TAP_FMA(A, V, cc) \
    A = fmaf(curv[(cc)*8+0], bf_lo((V).x), A); A = fmaf(curv[(cc)*8+1], bf_hi((V).x), A); \
    A = fmaf(curv[(cc)*8+2], bf_lo((V).y), A); A = fmaf(curv[(cc)*8+3], bf_hi((V).y), A); \
    A = fmaf(curv[(cc)*8+4], bf_lo((V).z), A); A = fmaf(curv[(cc)*8+5], bf_hi((V).z), A); \
    A = fmaf(curv[(cc)*8+6], bf_lo((V).w), A); A = fmaf(curv[(cc)*8+7], bf_hi((V).w), A);

// ---------- main: bf16-NHWC gather, ND=2 depths/thread, XCD-pinned b ----------
__global__ __launch_bounds__(256, 4) void cv_packed(
    const float* __restrict__ curT,          // (B, HW, C) fp32
    const unsigned short* __restrict__ srcT, // (B, K, HW, C) bf16
    const float* __restrict__ Emat,
    const float* __restrict__ Kmat,
    const float* __restrict__ invK,
    const float* __restrict__ mnp,
    const float* __restrict__ mxp,
    float* __restrict__ out)
{
    int blk  = blockIdx.x;
    int b    = blk & 7;          // XCD-pinned: all blocks of batch b on one XCD
    int r    = blk >> 3;
    int g    = r & (DG-1);       // depth group (fastest -> depth locality in L2)
    int tile = r >> 5;

    __shared__ float sM[KK][12];
    if (threadIdx.x < KK) {
        int k = threadIdx.x;
        const float* Km = Kmat + (size_t)(b*KK + k)*16;
        const float* Em = Emat + (size_t)(b*KK + k)*16;
        float P[3][4];
        #pragma unroll
        for (int i = 0; i < 3; ++i)
            #pragma unroll
            for (int jj = 0; jj < 4; ++jj) {
                float s = 0.f;
                #pragma unroll
                for (int l = 0; l < 4; ++l) s = fmaf(Km[i*4+l], Em[l*4+jj], s);
                P[i][jj] = s;
            }
        const float* iK = invK + (size_t)b*16;
        #pragma unroll
        for (int i = 0; i < 3; ++i) {
            #pragma unroll
            for (int jj = 0; jj < 3; ++jj) {
                float s = 0.f;
                #pragma unroll
                for (int l = 0; l < 3; ++l) s = fmaf(P[i][l], iK[l*4+jj], s);
                sM[k][i*4+jj] = s;
            }
            sM[k][i*4+3] = P[i][3];
        }
    }
    __syncthreads();

    int p  = tile*256 + threadIdx.x;
    float fx = (float)(p & (WW-1)) + 0.5f;
    float fy = (float)(p >> 7) + 0.5f;

    float curv[CC];
    {
        const float4* cp = reinterpret_cast<const float4*>(curT + ((size_t)b*HWSZ + p)*CC);
        #pragma unroll
        for (int i = 0; i < 8; ++i) {
            float4 f = cp[i];
            curv[4*i+0] = f.x; curv[4*i+1] = f.y; curv[4*i+2] = f.z; curv[4*i+3] = f.w;
        }
    }

    float mnb = mnp[b];
    float lmn = logf(mnb);
    float lr  = logf(mxp[b] / mnb);
    float d0 = expf(fmaf(lr, (float)(g*ND + 0) * (1.f/63.f), lmn));
    float d1 = expf(fmaf(lr, (float)(g*ND + 1) * (1.f/63.f), lmn));

    float acc0 = 0.f, acc1 = 0.f;

    for (int k = 0; k < KK; ++k) {
        float q0 = fmaf(sM[k][0], fx, fmaf(sM[k][1], fy, sM[k][2]));
        float q1 = fmaf(sM[k][4], fx, fmaf(sM[k][5], fy, sM[k][6]));
        float q2 = fmaf(sM[k][8], fx, fmaf(sM[k][9], fy, sM[k][10]));
        float m3 = sM[k][3], m7 = sM[k][7], m11 = sM[k][11];

        Tap A = project(d0, q0, q1, q2, m3, m7, m11);
        Tap B = project(d1, q0, q1, q2, m3, m7, m11);

        const char* sbb = reinterpret_cast<const char*>(srcT + (size_t)(b*KK + k)*HWSZ*CC);

        float a0=0.f,a1=0.f,a2=0.f,a3=0.f,a4=0.f,a5=0.f,a6=0.f,a7=0.f;
        #pragma unroll
        for (int cc = 0; cc < 4; ++cc) {
            uint4 v0 = *reinterpret_cast<const uint4*>(sbb + A.o0 + cc*16);
            uint4 v1 = *reinterpret_cast<const uint4*>(sbb + A.o1 + cc*16);
            uint4 v2 = *reinterpret_cast<const uint4*>(sbb + A.o2 + cc*16);
            uint4 v3 = *reinterpret_cast<const uint4*>(sbb + A.o3 + cc*16);
            uint4 v4 = *reinterpret_cast<const uint4*>(sbb + B.o0 + cc*16);
            uint4 v5 = *reinterpret_cast<const uint4*>(sbb + B.o1 + cc*16);
            uint4 v6 = *reinterpret_cast<const uint4*>(sbb + B.o2 + cc*16);
            uint4 v7 = *reinterpret_cast<const uint4*>(sbb + B.o3 + cc*16);
            TAP_FMA(a0, v0, cc)  TAP_FMA(a1, v1, cc)
            TAP_FMA(a2, v2, cc)  TAP_FMA(a3, v3, cc)
            TAP_FMA(a4, v4, cc)  TAP_FMA(a5, v5, cc)
            TAP_FMA(a6, v6, cc)  TAP_FMA(a7, v7, cc)
        }
        acc0 += A.w0*a0 + A.w1*a1 + A.w2*a2 + A.w3*a3;
        acc1 += B.w0*a4 + B.w1*a5 + B.w2*a6 + B.w3*a7;
    }

    out[(size_t)(b*DD + g*ND + 0)*HWSZ + p] = acc0;
    out[(size_t)(b*DD + g*ND + 1)*HWSZ + p] = acc1;
}

// ---------- fallback (ws too small): round-1 style, known correct ----------
__global__ __launch_bounds__(256) void cv_fallback(
    const float* __restrict__ cur, const float* __restrict__ src,
    const float* __restrict__ Emat, const float* __restrict__ Kmat,
    const float* __restrict__ invK, const float* __restrict__ mnp,
    const float* __restrict__ mxp, float* __restrict__ out)
{
    int blk  = blockIdx.x;
    int tile = blk % TILES;
    int bd   = blk / TILES;
    int d    = bd % DD;
    int b    = bd / DD;
    __shared__ float sM[KK][12];
    __shared__ float sDepth;
    if (threadIdx.x < KK) {
        int k = threadIdx.x;
        const float* Km = Kmat + (size_t)(b*KK + k)*16;
        const float* Em = Emat + (size_t)(b*KK + k)*16;
        float P[3][4];
        #pragma unroll
        for (int i = 0; i < 3; ++i)
            #pragma unroll
            for (int jj = 0; jj < 4; ++jj) {
                float s = 0.f;
                #pragma unroll
                for (int l = 0; l < 4; ++l) s = fmaf(Km[i*4+l], Em[l*4+jj], s);
                P[i][jj] = s;
            }
        const float* iK = invK + (size_t)b*16;
        #pragma unroll
        for (int i = 0; i < 3; ++i) {
            #pragma unroll
            for (int jj = 0; jj < 3; ++jj) {
                float s = 0.f;
                #pragma unroll
                for (int l = 0; l < 3; ++l) s = fmaf(P[i][l], iK[l*4+jj], s);
                sM[k][i*4+jj] = s;
            }
            sM[k][i*4+3] = P[i][3];
        }
    }
    if (threadIdx.x == KK) {
        float mnb = mnp[b], mxb = mxp[b];
        sDepth = expf(logf(mnb) + logf(mxb/mnb) * ((float)d * (1.f/63.f)));
    }
    __syncthreads();
    int p  = tile*256 + threadIdx.x;
    float fx = (float)(p & (WW-1)) + 0.5f;
    float fy = (float)(p >> 7) + 0.5f;
    float depth = sDepth;
    float curv[CC];
    const float* curp = cur + (size_t)b*CC*HWSZ + p;
    #pragma unroll
    for (int c = 0; c < CC; ++c) curv[c] = curp[(size_t)c*HWSZ];
    float acc = 0.f;
    for (int k = 0; k < KK; ++k) {
        float q0 = fmaf(sM[k][0], fx, fmaf(sM[k][1], fy, sM[k][2]));
        float q1 = fmaf(sM[k][4], fx, fmaf(sM[k][5], fy, sM[k][6]));
        float q2 = fmaf(sM[k][8], fx, fmaf(sM[k][9], fy, sM[k][10]));
        Tap t = project(depth, q0, q1, q2, sM[k][3], sM[k][7], sM[k][11]);
        const float* sb = src + (size_t)(b*KK + k)*CC*HWSZ;
        int o0 = (int)(t.o0/(CC*2)), o1 = (int)(t.o1/(CC*2));
        int o2 = (int)(t.o2/(CC*2)), o3 = (int)(t.o3/(CC*2));
        float a0=0.f,a1=0.f,a2=0.f,a3=0.f;
        #pragma unroll 8
        for (int c = 0; c < CC; ++c) {
            const float* sc = sb + (size_t)c*HWSZ;
            a0 = fmaf(curv[c], sc[o0], a0);
            a1 = fmaf(curv[c], sc[o1], a1);
            a2 = fmaf(curv[c], sc[o2], a2);
            a3 = fmaf(curv[c], sc[o3], a3);
        }
        acc += t.w0*a0 + t.w1*a1 + t.w2*a2 + t.w3*a3;
    }
    out[(size_t)(b*DD + d)*HWSZ + p] = acc;
}

extern "C" void kernel_launch(void* const* d_in, const int* in_sizes, int n_in,
                              void* d_out, int out_size, void* d_ws, size_t ws_size,
                              hipStream_t stream) {
    const float* cur   = (const float*)d_in[0];
    const float* srcf  = (const float*)d_in[1];
    const float* Emat  = (const float*)d_in[2];
    const float* Kmat  = (const float*)d_in[3];
    const float* invK  = (const float*)d_in[4];
    const float* mn    = (const float*)d_in[5];
    const float* mx    = (const float*)d_in[6];
    float* out = (float*)d_out;

    const size_t srcT_bytes = (size_t)BB*KK*HWSZ*CC*2;          // 44 MB bf16
    const size_t curT_bytes = (size_t)BB*HWSZ*CC*4;             // 12.6 MB fp32
    dim3 block(256);

    if (ws_size >= srcT_bytes + curT_bytes) {
        unsigned short* srcT = (unsigned short*)d_ws;
        float* curT = (float*)((char*)d_ws + srcT_bytes);
        pack_src<<<dim3(BB*KK*(HWSZ/32)), block, 0, stream>>>(srcf, srcT);
        pack_cur<<<dim3(BB*(HWSZ/32)),   block, 0, stream>>>(cur, curT);
        cv_packed<<<dim3(BB*DG*TILES), block, 0, stream>>>(curT, srcT, Emat, Kmat, invK, mn, mx, out);
    } else {
        cv_fallback<<<dim3(BB*DD*TILES), block, 0, stream>>>(cur, srcf, Emat, Kmat, invK, mn, mx, out);
    }
}